// Round 2
// baseline (458.804 us; speedup 1.0000x reference)
//
#include <hip/hip_runtime.h>
#include <stdint.h>

#define D_DIM 1024
#define H_DIM 512
#define NEXP  8
#define NP    10            // 8 routed + 2 shared expert passes
#define KCAT  (NP * H_DIM)  // 5120

#define BM 128
#define BN 64
#define BK 64
#define LDK 72              // BK + 8 pad -> 144B row stride (16B aligned)

typedef __attribute__((ext_vector_type(8))) short short8;     // 8 bf16 MFMA operand
typedef __attribute__((ext_vector_type(4))) float floatx4;    // MFMA accumulator
typedef __attribute__((ext_vector_type(4))) unsigned int uint4v;
typedef __attribute__((ext_vector_type(4))) float float4v;

__device__ __forceinline__ float bf2f(unsigned short u) {
    union { float f; unsigned int i; } v; v.i = ((unsigned int)u) << 16; return v.f;
}
__device__ __forceinline__ unsigned short f2bf(float f) {
    union { float f; unsigned int i; } v; v.f = f;
    unsigned int r = v.i + 0x7FFFu + ((v.i >> 16) & 1u);   // RNE
    return (unsigned short)(r >> 16);
}

// ---------------------------------------------------------------------------
// Dtype detection: if x is really fp32 read as bf16 shorts, mantissa halves
// have uniform exponent bits -> values with e>=0xA0 (|v|>2^33) are certain.
// Genuine bf16 N(0,1) data never exceeds e~0x81. flag=1 -> inputs are fp32.
// ---------------------------------------------------------------------------
__global__ void detect_kernel(const unsigned short* __restrict__ x, int* flag)
{
    __shared__ int bad;
    if (threadIdx.x == 0) bad = 0;
    __syncthreads();
    int b = 0;
    for (int i = threadIdx.x; i < 8192; i += 256) {
        int e = (x[i] >> 7) & 0xFF;
        if (e >= 0xA0) b = 1;
    }
    if (b) atomicOr(&bad, 1);
    __syncthreads();
    if (threadIdx.x == 0) *flag = bad;
}

// ---------------------------------------------------------------------------
// Router: one wave per token. logits = x @ rw + rb (fp32), top-2 softmax.
// gscale layout [NP][T]: cols 0..7 = sparse gates, 8..9 = 1.0 (shared).
// ---------------------------------------------------------------------------
__global__ __launch_bounds__(256, 4) void router_kernel(
    const void* __restrict__ xv_, const void* __restrict__ rwv_,
    const void* __restrict__ rbv_, const int* __restrict__ flag,
    float* __restrict__ gscale, int T)
{
    const int isf32 = *flag;
    int gid  = blockIdx.x * blockDim.x + threadIdx.x;
    int t    = gid >> 6;
    int lane = threadIdx.x & 63;
    if (t >= T) return;

    float acc[NEXP];
#pragma unroll
    for (int e = 0; e < NEXP; e++) acc[e] = 0.f;

    if (isf32) {
        const float* xr = (const float*)xv_ + (size_t)t * D_DIM;
        const float* rw = (const float*)rwv_;
#pragma unroll 4
        for (int i = 0; i < D_DIM / 64; i++) {
            int d = i * 64 + lane;
            float xv = xr[d];
            float4v wa = *(const float4v*)(rw + (size_t)d * NEXP);
            float4v wb = *(const float4v*)(rw + (size_t)d * NEXP + 4);
#pragma unroll
            for (int q = 0; q < 4; q++) { acc[q] += xv * wa[q]; acc[q + 4] += xv * wb[q]; }
        }
    } else {
        const unsigned short* xr = (const unsigned short*)xv_ + (size_t)t * D_DIM;
        const unsigned short* rw = (const unsigned short*)rwv_;
#pragma unroll 4
        for (int i = 0; i < D_DIM / 64; i++) {
            int d = i * 64 + lane;
            float xv = bf2f(xr[d]);
            uint4v wv = *(const uint4v*)(rw + (size_t)d * NEXP);
#pragma unroll
            for (int q = 0; q < 4; q++) {
                unsigned int w = wv[q];
                acc[q * 2 + 0] += xv * bf2f((unsigned short)(w & 0xFFFFu));
                acc[q * 2 + 1] += xv * bf2f((unsigned short)(w >> 16));
            }
        }
    }
#pragma unroll
    for (int m = 32; m >= 1; m >>= 1) {
#pragma unroll
        for (int e = 0; e < NEXP; e++) acc[e] += __shfl_xor(acc[e], m, 64);
    }
    if (lane == 0) {
#pragma unroll
        for (int e = 0; e < NEXP; e++)
            acc[e] += isf32 ? ((const float*)rbv_)[e] : bf2f(((const unsigned short*)rbv_)[e]);
        int i1 = 0; float v1 = acc[0];
#pragma unroll
        for (int e = 1; e < NEXP; e++) if (acc[e] > v1) { v1 = acc[e]; i1 = e; }
        int i2 = -1; float v2 = -3.4e38f;
#pragma unroll
        for (int e = 0; e < NEXP; e++) if (e != i1 && acc[e] > v2) { v2 = acc[e]; i2 = e; }
        float g1 = 1.f / (1.f + __expf(v2 - v1));   // v2 <= v1: stable
        float g2 = 1.f - g1;
#pragma unroll
        for (int e = 0; e < NEXP; e++)
            gscale[(size_t)e * T + t] = (e == i1) ? g1 : ((e == i2) ? g2 : 0.f);
        gscale[(size_t)8 * T + t] = 1.f;
        gscale[(size_t)9 * T + t] = 1.f;
    }
}

// ---------------------------------------------------------------------------
// Stage A: per expert-pass dual GEMM + SwiGLU + gate scale.
// A_out[t, p*512 + h] = gate[p][t] * silu(x@w1_p)[t,h] * (x@w3_p)[t,h]  (bf16)
// ---------------------------------------------------------------------------
__global__ __launch_bounds__(256, 2) void moe_h_kernel(
    const void* __restrict__ x_,      // [T, D]
    const void* __restrict__ rw1_,    // [8, D, H]
    const void* __restrict__ rw3_,    // [8, D, H]
    const void* __restrict__ sw1_,    // [2, D, H]
    const void* __restrict__ sw3_,    // [2, D, H]
    const int*  __restrict__ flag,
    const float* __restrict__ gscale, // [NP, T]
    unsigned short* __restrict__ aout,// [Tc, KCAT] (chunk-local)
    int T, int t0g)
{
    __shared__ __align__(16) unsigned short lA[BM][LDK];
    __shared__ __align__(16) unsigned short lB1[BN][LDK];
    __shared__ __align__(16) unsigned short lB3[BN][LDK];

    const int isf32 = *flag;
    const int tid = threadIdx.x;
    const int pm = blockIdx.x, pn = blockIdx.y, p = blockIdx.z;
    const size_t woff = (p < 8) ? (size_t)p * D_DIM * H_DIM
                                : (size_t)(p - 8) * D_DIM * H_DIM;
    const void* w1_ = (p < 8) ? rw1_ : sw1_;
    const void* w3_ = (p < 8) ? rw3_ : sw3_;
    const int n0 = pn * BN;
    const size_t xrow0 = (size_t)(t0g + pm * BM) * D_DIM;

    floatx4 acc1[4][2], acc3[4][2];
#pragma unroll
    for (int fm = 0; fm < 4; fm++)
#pragma unroll
        for (int fn = 0; fn < 2; fn++) {
            floatx4 z = {0.f, 0.f, 0.f, 0.f};
            acc1[fm][fn] = z; acc3[fm][fn] = z;
        }

    const int wave = tid >> 6, lane = tid & 63;
    const int wm = (wave >> 1) * 64, wn = (wave & 1) * 32;
    const int lm = lane & 15, lq = lane >> 4;

    for (int k0 = 0; k0 < D_DIM; k0 += BK) {
        // ---- stage A tile [BM][BK]
        if (isf32) {
            const float* xf = (const float*)x_;
#pragma unroll
            for (int i = 0; i < 4; i++) {
                int idx = tid + i * 256;
                int m = idx >> 3, kv = (idx & 7) * 8;
                float b[8];
                *(float4v*)&b[0] = *(const float4v*)(xf + xrow0 + (size_t)m * D_DIM + k0 + kv);
                *(float4v*)&b[4] = *(const float4v*)(xf + xrow0 + (size_t)m * D_DIM + k0 + kv + 4);
                uint4v v;
#pragma unroll
                for (int j = 0; j < 4; j++)
                    v[j] = (unsigned)f2bf(b[2 * j]) | ((unsigned)f2bf(b[2 * j + 1]) << 16);
                *(uint4v*)&lA[m][kv] = v;
            }
        } else {
            const unsigned short* xb = (const unsigned short*)x_;
#pragma unroll
            for (int i = 0; i < 4; i++) {
                int idx = tid + i * 256;
                int m = idx >> 3, kv = (idx & 7) * 8;
                *(uint4v*)&lA[m][kv] =
                    *(const uint4v*)(xb + xrow0 + (size_t)m * D_DIM + k0 + kv);
            }
        }
        // ---- stage B1/B3 transposed into [n][k]
        if (isf32) {
            const float* w1 = (const float*)w1_ + woff;
            const float* w3 = (const float*)w3_ + woff;
#pragma unroll
            for (int i = 0; i < 2; i++) {
                int idx = tid + i * 256;
                int n = idx & 63, kc = (idx >> 6) * 8;
                uint4v v1, v3;
#pragma unroll
                for (int j = 0; j < 4; j++) {
                    size_t o0 = (size_t)(k0 + kc + 2 * j) * H_DIM + n0 + n;
                    size_t o1 = o0 + H_DIM;
                    v1[j] = (unsigned)f2bf(w1[o0]) | ((unsigned)f2bf(w1[o1]) << 16);
                    v3[j] = (unsigned)f2bf(w3[o0]) | ((unsigned)f2bf(w3[o1]) << 16);
                }
                *(uint4v*)&lB1[n][kc] = v1;
                *(uint4v*)&lB3[n][kc] = v3;
            }
        } else {
            const unsigned short* w1 = (const unsigned short*)w1_ + woff;
            const unsigned short* w3 = (const unsigned short*)w3_ + woff;
#pragma unroll
            for (int i = 0; i < 2; i++) {
                int idx = tid + i * 256;
                int n = idx & 63, kc = (idx >> 6) * 8;
                uint4v v1, v3;
#pragma unroll
                for (int j = 0; j < 4; j++) {
                    size_t o0 = (size_t)(k0 + kc + 2 * j) * H_DIM + n0 + n;
                    size_t o1 = o0 + H_DIM;
                    v1[j] = (unsigned)w1[o0] | ((unsigned)w1[o1] << 16);
                    v3[j] = (unsigned)w3[o0] | ((unsigned)w3[o1] << 16);
                }
                *(uint4v*)&lB1[n][kc] = v1;
                *(uint4v*)&lB3[n][kc] = v3;
            }
        }
        __syncthreads();
#pragma unroll
        for (int kk = 0; kk < BK; kk += 32) {
            short8 af[4], b1f[2], b3f[2];
#pragma unroll
            for (int fm = 0; fm < 4; fm++)
                af[fm] = *(const short8*)&lA[wm + fm * 16 + lm][kk + lq * 8];
#pragma unroll
            for (int fn = 0; fn < 2; fn++) {
                b1f[fn] = *(const short8*)&lB1[wn + fn * 16 + lm][kk + lq * 8];
                b3f[fn] = *(const short8*)&lB3[wn + fn * 16 + lm][kk + lq * 8];
            }
#pragma unroll
            for (int fm = 0; fm < 4; fm++)
#pragma unroll
                for (int fn = 0; fn < 2; fn++) {
                    acc1[fm][fn] = __builtin_amdgcn_mfma_f32_16x16x32_bf16(
                        af[fm], b1f[fn], acc1[fm][fn], 0, 0, 0);
                    acc3[fm][fn] = __builtin_amdgcn_mfma_f32_16x16x32_bf16(
                        af[fm], b3f[fn], acc3[fm][fn], 0, 0, 0);
                }
        }
        __syncthreads();
    }

    // epilogue: silu(a1)*a3*gate -> bf16.  C/D map: col=lane&15, row=lq*4+reg.
    const float* gs = gscale + (size_t)p * T + t0g + pm * BM;
#pragma unroll
    for (int fm = 0; fm < 4; fm++) {
#pragma unroll
        for (int r = 0; r < 4; r++) {
            int row = wm + fm * 16 + lq * 4 + r;
            float g = gs[row];
#pragma unroll
            for (int fn = 0; fn < 2; fn++) {
                float a1 = acc1[fm][fn][r], a3 = acc3[fm][fn][r];
                float h = a1 / (1.f + __expf(-a1)) * a3 * g;
                int col = wn + fn * 16 + lm;
                aout[(size_t)(pm * BM + row) * KCAT + p * H_DIM + n0 + col] = f2bf(h);
            }
        }
    }
}

// ---------------------------------------------------------------------------
// Stage B: out[T,1024] = A_all[T,5120] @ concat(w2)[5120,1024]  (fp32 acc)
// ---------------------------------------------------------------------------
__global__ __launch_bounds__(256, 2) void moe_out_kernel(
    const unsigned short* __restrict__ Ain,   // [Tc, KCAT] (chunk-local)
    const void* __restrict__ rw2_,            // [8, H, D]
    const void* __restrict__ sw2_,            // [2, H, D]
    const int*  __restrict__ flag,
    void* __restrict__ out_,                  // [T, D]
    int t0g)
{
    __shared__ __align__(16) unsigned short lA[BM][LDK];
    __shared__ __align__(16) unsigned short lB[BN][LDK];

    const int isf32 = *flag;
    const int tid = threadIdx.x;
    const int pm = blockIdx.x, pn = blockIdx.y;
    const int n0 = pn * BN;

    floatx4 acc[4][2];
#pragma unroll
    for (int fm = 0; fm < 4; fm++)
#pragma unroll
        for (int fn = 0; fn < 2; fn++) {
            floatx4 z = {0.f, 0.f, 0.f, 0.f};
            acc[fm][fn] = z;
        }

    const int wave = tid >> 6, lane = tid & 63;
    const int wm = (wave >> 1) * 64, wn = (wave & 1) * 32;
    const int lm = lane & 15, lq = lane >> 4;

    for (int k0 = 0; k0 < KCAT; k0 += BK) {
        int p  = k0 >> 9;          // /H_DIM
        int ko = k0 & (H_DIM - 1);
        const size_t woff = (p < 8) ? (size_t)p * H_DIM * D_DIM
                                    : (size_t)(p - 8) * H_DIM * D_DIM;
        const void* w2_ = (p < 8) ? rw2_ : sw2_;
#pragma unroll
        for (int i = 0; i < 4; i++) {
            int idx = tid + i * 256;
            int m = idx >> 3, kv = (idx & 7) * 8;
            *(uint4v*)&lA[m][kv] =
                *(const uint4v*)(Ain + (size_t)(pm * BM + m) * KCAT + k0 + kv);
        }
        if (isf32) {
            const float* w2 = (const float*)w2_ + woff;
#pragma unroll
            for (int i = 0; i < 2; i++) {
                int idx = tid + i * 256;
                int n = idx & 63, kc = (idx >> 6) * 8;
                uint4v v;
#pragma unroll
                for (int j = 0; j < 4; j++) {
                    size_t o0 = (size_t)(ko + kc + 2 * j) * D_DIM + n0 + n;
                    size_t o1 = o0 + D_DIM;
                    v[j] = (unsigned)f2bf(w2[o0]) | ((unsigned)f2bf(w2[o1]) << 16);
                }
                *(uint4v*)&lB[n][kc] = v;
            }
        } else {
            const unsigned short* w2 = (const unsigned short*)w2_ + woff;
#pragma unroll
            for (int i = 0; i < 2; i++) {
                int idx = tid + i * 256;
                int n = idx & 63, kc = (idx >> 6) * 8;
                uint4v v;
#pragma unroll
                for (int j = 0; j < 4; j++) {
                    size_t o0 = (size_t)(ko + kc + 2 * j) * D_DIM + n0 + n;
                    size_t o1 = o0 + D_DIM;
                    v[j] = (unsigned)w2[o0] | ((unsigned)w2[o1] << 16);
                }
                *(uint4v*)&lB[n][kc] = v;
            }
        }
        __syncthreads();
#pragma unroll
        for (int kk = 0; kk < BK; kk += 32) {
            short8 af[4], bf[2];
#pragma unroll
            for (int fm = 0; fm < 4; fm++)
                af[fm] = *(const short8*)&lA[wm + fm * 16 + lm][kk + lq * 8];
#pragma unroll
            for (int fn = 0; fn < 2; fn++)
                bf[fn] = *(const short8*)&lB[wn + fn * 16 + lm][kk + lq * 8];
#pragma unroll
            for (int fm = 0; fm < 4; fm++)
#pragma unroll
                for (int fn = 0; fn < 2; fn++)
                    acc[fm][fn] = __builtin_amdgcn_mfma_f32_16x16x32_bf16(
                        af[fm], bf[fn], acc[fm][fn], 0, 0, 0);
        }
        __syncthreads();
    }

#pragma unroll
    for (int fm = 0; fm < 4; fm++)
#pragma unroll
        for (int r = 0; r < 4; r++) {
            int row = wm + fm * 16 + lq * 4 + r;
#pragma unroll
            for (int fn = 0; fn < 2; fn++) {
                int col = wn + fn * 16 + lm;
                size_t off = (size_t)(t0g + pm * BM + row) * D_DIM + n0 + col;
                float val = acc[fm][fn][r];
                if (isf32) ((float*)out_)[off] = val;
                else       ((unsigned short*)out_)[off] = f2bf(val);
            }
        }
}

// ---------------------------------------------------------------------------
extern "C" void kernel_launch(void* const* d_in, const int* in_sizes, int n_in,
                              void* d_out, int out_size, void* d_ws, size_t ws_size,
                              hipStream_t stream)
{
    const void* x   = d_in[0];
    const void* rw  = d_in[1];
    const void* rb  = d_in[2];
    const void* rw1 = d_in[3];
    const void* rw3 = d_in[4];
    const void* rw2 = d_in[5];
    const void* sw1 = d_in[6];
    const void* sw3 = d_in[7];
    const void* sw2 = d_in[8];

    const int T = in_sizes[0] / D_DIM;   // 4096

    // ws layout: flag(256B) | gscale fp32 [NP][T] | A_all bf16 [Tc][KCAT]
    int* flag = (int*)d_ws;
    float* gscale = (float*)((char*)d_ws + 256);
    size_t gbytes = 256 + ((((size_t)NP * T * sizeof(float)) + 255) & ~(size_t)255);
    unsigned short* A_all = (unsigned short*)((char*)d_ws + gbytes);
    size_t avail = (ws_size > gbytes) ? ws_size - gbytes : 0;
    size_t per_tok = (size_t)KCAT * sizeof(unsigned short);
    long long tc = (long long)(avail / per_tok);
    int Tc = (int)((tc / BM) * BM);
    if (Tc > T) Tc = T;
    if (Tc < BM) Tc = BM;   // last resort; assumes ws >= ~1.6MB

    detect_kernel<<<1, 256, 0, stream>>>((const unsigned short*)x, flag);
    router_kernel<<<dim3((T * 64 + 255) / 256), 256, 0, stream>>>(x, rw, rb, flag, gscale, T);

    for (int t0 = 0; t0 < T; t0 += Tc) {
        int ct = (T - t0 < Tc) ? (T - t0) : Tc;
        dim3 g2(ct / BM, H_DIM / BN, NP);
        moe_h_kernel<<<g2, 256, 0, stream>>>(x, rw1, rw3, sw1, sw3, flag, gscale, A_all, T, t0);
        dim3 g3(ct / BM, D_DIM / BN);
        moe_out_kernel<<<g3, 256, 0, stream>>>(A_all, rw2, sw2, flag, d_out, t0);
    }
}

// Round 3
// 454.587 us; speedup vs baseline: 1.0093x; 1.0093x over previous
//
#include <hip/hip_runtime.h>
#include <stdint.h>

#define D_DIM 1024
#define H_DIM 512
#define NEXP  8
#define NP    10            // 8 routed + 2 shared expert passes

#define BM 128
#define BN 64
#define BK 64
#define LDK 72              // BK + 8 pad -> 144B row stride (16B aligned)

typedef __attribute__((ext_vector_type(8))) short short8;     // 8 bf16 MFMA operand
typedef __attribute__((ext_vector_type(4))) float floatx4;    // MFMA accumulator
typedef __attribute__((ext_vector_type(4))) unsigned int uint4v;
typedef __attribute__((ext_vector_type(4))) float float4v;
typedef __attribute__((ext_vector_type(2))) unsigned int uint2v;

__device__ __forceinline__ float bf2f(unsigned short u) {
    union { float f; unsigned int i; } v; v.i = ((unsigned int)u) << 16; return v.f;
}
__device__ __forceinline__ unsigned short f2bf(float f) {
    union { float f; unsigned int i; } v; v.f = f;
    unsigned int r = v.i + 0x7FFFu + ((v.i >> 16) & 1u);   // RNE
    return (unsigned short)(r >> 16);
}

// ---------------------------------------------------------------------------
// Dtype detection (fp32-read-as-bf16 has uniform exponents -> e>=0xA0 certain)
// ---------------------------------------------------------------------------
__global__ void detect_kernel(const unsigned short* __restrict__ x, int* flag)
{
    __shared__ int bad;
    if (threadIdx.x == 0) bad = 0;
    __syncthreads();
    int b = 0;
    for (int i = threadIdx.x; i < 8192; i += 256) {
        int e = (x[i] >> 7) & 0xFF;
        if (e >= 0xA0) b = 1;
    }
    if (b) atomicOr(&bad, 1);
    __syncthreads();
    if (threadIdx.x == 0) *flag = bad;
}

// ---------------------------------------------------------------------------
// init: zero expert counters + slot lists (padding slots must be token0/gate0)
// ---------------------------------------------------------------------------
__global__ void init_kernel(int* __restrict__ cnt, int* __restrict__ toklist,
                            float* __restrict__ slotgate, int slotmax)
{
    int i = blockIdx.x * 256 + threadIdx.x;
    if (i < slotmax) { toklist[i] = 0; slotgate[i] = 0.f; }
    if (blockIdx.x == 0 && threadIdx.x < NEXP) cnt[threadIdx.x] = 0;
}

// ---------------------------------------------------------------------------
// Weight transpose+convert: src [nmat][K][N] (fp32 or bf16) -> dst bf16 [nmat][N][K]
// block: 256 thr covers [64 n][32 k]; grid (K/32, N/64, 10). z<8 routed, else shared.
// ---------------------------------------------------------------------------
__global__ __launch_bounds__(256) void transp_kernel(
    const void* __restrict__ rsrc, const void* __restrict__ ssrc,
    unsigned short* __restrict__ dst, int K, int N, const int* __restrict__ flag)
{
    const int isf32 = *flag;
    const int z = blockIdx.z;
    const size_t moff = (size_t)(z < 8 ? z : z - 8) * K * N;
    const int nl = threadIdx.x & 63, j = threadIdx.x >> 6;
    const int n = blockIdx.y * 64 + nl;
    const int k0 = blockIdx.x * 32 + j * 8;

    unsigned short v[8];
    if (isf32) {
        const float* src = (const float*)(z < 8 ? rsrc : ssrc) + moff;
#pragma unroll
        for (int j2 = 0; j2 < 8; j2++) v[j2] = f2bf(src[(size_t)(k0 + j2) * N + n]);
    } else {
        const unsigned short* src = (const unsigned short*)(z < 8 ? rsrc : ssrc) + moff;
#pragma unroll
        for (int j2 = 0; j2 < 8; j2++) v[j2] = src[(size_t)(k0 + j2) * N + n];
    }
    uint4v w;
#pragma unroll
    for (int q = 0; q < 4; q++) w[q] = (unsigned)v[2 * q] | ((unsigned)v[2 * q + 1] << 16);
    *(uint4v*)(dst + ((size_t)z * N + n) * K + k0) = w;
}

// ---------------------------------------------------------------------------
// Router: one wave per token -> top-2 (expert ids, softmax gates), count tokens.
// ---------------------------------------------------------------------------
__global__ __launch_bounds__(256, 4) void router_kernel(
    const void* __restrict__ xv_, const void* __restrict__ rwv_,
    const void* __restrict__ rbv_, const int* __restrict__ flag,
    int* __restrict__ topkE, float2* __restrict__ topkG,
    int* __restrict__ cnt, int T)
{
    const int isf32 = *flag;
    int gid  = blockIdx.x * blockDim.x + threadIdx.x;
    int t    = gid >> 6;
    int lane = threadIdx.x & 63;
    if (t >= T) return;

    float acc[NEXP];
#pragma unroll
    for (int e = 0; e < NEXP; e++) acc[e] = 0.f;

    if (isf32) {
        const float* xr = (const float*)xv_ + (size_t)t * D_DIM;
        const float* rw = (const float*)rwv_;
#pragma unroll 4
        for (int i = 0; i < D_DIM / 64; i++) {
            int d = i * 64 + lane;
            float xv = xr[d];
            float4v wa = *(const float4v*)(rw + (size_t)d * NEXP);
            float4v wb = *(const float4v*)(rw + (size_t)d * NEXP + 4);
#pragma unroll
            for (int q = 0; q < 4; q++) { acc[q] += xv * wa[q]; acc[q + 4] += xv * wb[q]; }
        }
    } else {
        const unsigned short* xr = (const unsigned short*)xv_ + (size_t)t * D_DIM;
        const unsigned short* rw = (const unsigned short*)rwv_;
#pragma unroll 4
        for (int i = 0; i < D_DIM / 64; i++) {
            int d = i * 64 + lane;
            float xv = bf2f(xr[d]);
            uint4v wv = *(const uint4v*)(rw + (size_t)d * NEXP);
#pragma unroll
            for (int q = 0; q < 4; q++) {
                unsigned int w = wv[q];
                acc[q * 2 + 0] += xv * bf2f((unsigned short)(w & 0xFFFFu));
                acc[q * 2 + 1] += xv * bf2f((unsigned short)(w >> 16));
            }
        }
    }
#pragma unroll
    for (int m = 32; m >= 1; m >>= 1) {
#pragma unroll
        for (int e = 0; e < NEXP; e++) acc[e] += __shfl_xor(acc[e], m, 64);
    }
    if (lane == 0) {
#pragma unroll
        for (int e = 0; e < NEXP; e++)
            acc[e] += isf32 ? ((const float*)rbv_)[e] : bf2f(((const unsigned short*)rbv_)[e]);
        int i1 = 0; float v1 = acc[0];
#pragma unroll
        for (int e = 1; e < NEXP; e++) if (acc[e] > v1) { v1 = acc[e]; i1 = e; }
        int i2 = -1; float v2 = -3.4e38f;
#pragma unroll
        for (int e = 0; e < NEXP; e++) if (e != i1 && acc[e] > v2) { v2 = acc[e]; i2 = e; }
        float g1 = 1.f / (1.f + __expf(v2 - v1));   // v2 <= v1: stable softmax2
        float g2 = 1.f - g1;
        topkE[t] = i1 | (i2 << 8);
        float2 g; g.x = g1; g.y = g2;
        topkG[t] = g;
        atomicAdd(&cnt[i1], 1);
        atomicAdd(&cnt[i2], 1);
    }
}

// ---------------------------------------------------------------------------
// seg: offsets (padded to BM) + segment descriptors. Single thread (8 experts).
// ---------------------------------------------------------------------------
__global__ void seg_kernel(const int* __restrict__ cnt, int* __restrict__ fill,
                           int2* __restrict__ segdesc, int* __restrict__ nseg)
{
    if (threadIdx.x != 0 || blockIdx.x != 0) return;
    int off = 0, ns = 0;
    for (int e = 0; e < NEXP; e++) {
        int c = cnt[e];
        fill[e] = off;
        int nsg = (c + BM - 1) / BM;
        for (int j = 0; j < nsg; j++) { int2 s; s.x = e; s.y = off + j * BM; segdesc[ns++] = s; }
        off += nsg * BM;
    }
    *nseg = ns;
}

// ---------------------------------------------------------------------------
// gather: fill per-expert slot lists; record each token's two slots.
// ---------------------------------------------------------------------------
__global__ void gather_kernel(const int* __restrict__ topkE, const float2* __restrict__ topkG,
                              int* __restrict__ fill, int* __restrict__ toklist,
                              float* __restrict__ slotgate, int2* __restrict__ slotof, int T)
{
    int t = blockIdx.x * 256 + threadIdx.x;
    if (t >= T) return;
    int pk = topkE[t];
    float2 g = topkG[t];
    int e0 = pk & 255, e1 = pk >> 8;
    int s0 = atomicAdd(&fill[e0], 1);
    toklist[s0] = t; slotgate[s0] = g.x;
    int s1 = atomicAdd(&fill[e1], 1);
    toklist[s1] = t; slotgate[s1] = g.y;
    int2 so; so.x = s0; so.y = s1;
    slotof[t] = so;
}

// ---------------------------------------------------------------------------
// Shared-expert hidden: A_shared[t, z*512+h] = silu(x@w1_sh)*(x@w3_sh)  (bf16)
// grid (T/BM, H/BN, 2)
// ---------------------------------------------------------------------------
__global__ __launch_bounds__(256, 2) void moe_h_shared_kernel(
    const void* __restrict__ x_, const unsigned short* __restrict__ w1t,
    const unsigned short* __restrict__ w3t, const int* __restrict__ flag,
    unsigned short* __restrict__ Abuf)
{
    __shared__ __align__(16) unsigned short lA[BM][LDK];
    __shared__ __align__(16) unsigned short lB1[BN][LDK];
    __shared__ __align__(16) unsigned short lB3[BN][LDK];

    const int isf32 = *flag;
    const int tid = threadIdx.x;
    const int t0 = blockIdx.x * BM, n0 = blockIdx.y * BN, z = blockIdx.z;
    const unsigned short* W1 = w1t + (size_t)(8 + z) * H_DIM * D_DIM;  // [512][1024]
    const unsigned short* W3 = w3t + (size_t)(8 + z) * H_DIM * D_DIM;

    floatx4 acc1[4][2], acc3[4][2];
#pragma unroll
    for (int fm = 0; fm < 4; fm++)
#pragma unroll
        for (int fn = 0; fn < 2; fn++) {
            floatx4 zz = {0.f, 0.f, 0.f, 0.f};
            acc1[fm][fn] = zz; acc3[fm][fn] = zz;
        }
    const int wave = tid >> 6, lane = tid & 63;
    const int wm = (wave >> 1) * 64, wn = (wave & 1) * 32;
    const int lm = lane & 15, lq = lane >> 4;

    for (int k0 = 0; k0 < D_DIM; k0 += BK) {
        if (isf32) {
            const float* xf = (const float*)x_;
#pragma unroll
            for (int i = 0; i < 4; i++) {
                int m = (tid >> 3) + i * 32, kv = (tid & 7) * 8;
                const float* src = xf + (size_t)(t0 + m) * D_DIM + k0 + kv;
                float4v a = *(const float4v*)src, b = *(const float4v*)(src + 4);
                uint4v v;
#pragma unroll
                for (int q = 0; q < 2; q++) {
                    v[q]     = (unsigned)f2bf(a[2 * q]) | ((unsigned)f2bf(a[2 * q + 1]) << 16);
                    v[q + 2] = (unsigned)f2bf(b[2 * q]) | ((unsigned)f2bf(b[2 * q + 1]) << 16);
                }
                *(uint4v*)&lA[m][kv] = v;
            }
        } else {
            const unsigned short* xb = (const unsigned short*)x_;
#pragma unroll
            for (int i = 0; i < 4; i++) {
                int m = (tid >> 3) + i * 32, kv = (tid & 7) * 8;
                *(uint4v*)&lA[m][kv] = *(const uint4v*)(xb + (size_t)(t0 + m) * D_DIM + k0 + kv);
            }
        }
#pragma unroll
        for (int i = 0; i < 2; i++) {
            int n = (tid >> 3) + i * 32, kc = (tid & 7) * 8;
            *(uint4v*)&lB1[n][kc] = *(const uint4v*)(W1 + (size_t)(n0 + n) * D_DIM + k0 + kc);
            *(uint4v*)&lB3[n][kc] = *(const uint4v*)(W3 + (size_t)(n0 + n) * D_DIM + k0 + kc);
        }
        __syncthreads();
#pragma unroll
        for (int kk = 0; kk < BK; kk += 32) {
            short8 af[4], b1f[2], b3f[2];
#pragma unroll
            for (int fm = 0; fm < 4; fm++) af[fm] = *(const short8*)&lA[wm + fm * 16 + lm][kk + lq * 8];
#pragma unroll
            for (int fn = 0; fn < 2; fn++) {
                b1f[fn] = *(const short8*)&lB1[wn + fn * 16 + lm][kk + lq * 8];
                b3f[fn] = *(const short8*)&lB3[wn + fn * 16 + lm][kk + lq * 8];
            }
#pragma unroll
            for (int fm = 0; fm < 4; fm++)
#pragma unroll
                for (int fn = 0; fn < 2; fn++) {
                    acc1[fm][fn] = __builtin_amdgcn_mfma_f32_16x16x32_bf16(af[fm], b1f[fn], acc1[fm][fn], 0, 0, 0);
                    acc3[fm][fn] = __builtin_amdgcn_mfma_f32_16x16x32_bf16(af[fm], b3f[fn], acc3[fm][fn], 0, 0, 0);
                }
        }
        __syncthreads();
    }
#pragma unroll
    for (int fm = 0; fm < 4; fm++)
#pragma unroll
        for (int r = 0; r < 4; r++) {
            int row = wm + fm * 16 + lq * 4 + r;
#pragma unroll
            for (int fn = 0; fn < 2; fn++) {
                float a1 = acc1[fm][fn][r], a3 = acc3[fm][fn][r];
                float h = a1 / (1.f + __expf(-a1)) * a3;
                int col = wn + fn * 16 + lm;
                Abuf[(size_t)(t0 + row) * (2 * H_DIM) + z * H_DIM + n0 + col] = f2bf(h);
            }
        }
}

// ---------------------------------------------------------------------------
// Routed hidden: gathered token rows, gate folded in. grid (maxseg, H/BN)
// A_routed[slot, h]
// ---------------------------------------------------------------------------
__global__ __launch_bounds__(256, 2) void moe_h_routed_kernel(
    const void* __restrict__ x_, const unsigned short* __restrict__ w1t,
    const unsigned short* __restrict__ w3t, const int* __restrict__ flag,
    const int* __restrict__ toklist, const float* __restrict__ slotgate,
    const int2* __restrict__ segdesc, const int* __restrict__ nseg,
    unsigned short* __restrict__ Abuf)
{
    __shared__ __align__(16) unsigned short lA[BM][LDK];
    __shared__ __align__(16) unsigned short lB1[BN][LDK];
    __shared__ __align__(16) unsigned short lB3[BN][LDK];
    __shared__ int   lT[BM];
    __shared__ float lG[BM];

    const int s = blockIdx.x;
    if (s >= *nseg) return;
    const int isf32 = *flag;
    const int tid = threadIdx.x;
    const int2 sd = segdesc[s];
    const int e = sd.x, slot0 = sd.y;
    const int n0 = blockIdx.y * BN;
    const unsigned short* W1 = w1t + (size_t)e * H_DIM * D_DIM;
    const unsigned short* W3 = w3t + (size_t)e * H_DIM * D_DIM;

    if (tid < BM) { lT[tid] = toklist[slot0 + tid]; lG[tid] = slotgate[slot0 + tid]; }
    __syncthreads();

    floatx4 acc1[4][2], acc3[4][2];
#pragma unroll
    for (int fm = 0; fm < 4; fm++)
#pragma unroll
        for (int fn = 0; fn < 2; fn++) {
            floatx4 zz = {0.f, 0.f, 0.f, 0.f};
            acc1[fm][fn] = zz; acc3[fm][fn] = zz;
        }
    const int wave = tid >> 6, lane = tid & 63;
    const int wm = (wave >> 1) * 64, wn = (wave & 1) * 32;
    const int lm = lane & 15, lq = lane >> 4;

    for (int k0 = 0; k0 < D_DIM; k0 += BK) {
        if (isf32) {
            const float* xf = (const float*)x_;
#pragma unroll
            for (int i = 0; i < 4; i++) {
                int m = (tid >> 3) + i * 32, kv = (tid & 7) * 8;
                const float* src = xf + (size_t)lT[m] * D_DIM + k0 + kv;
                float4v a = *(const float4v*)src, b = *(const float4v*)(src + 4);
                uint4v v;
#pragma unroll
                for (int q = 0; q < 2; q++) {
                    v[q]     = (unsigned)f2bf(a[2 * q]) | ((unsigned)f2bf(a[2 * q + 1]) << 16);
                    v[q + 2] = (unsigned)f2bf(b[2 * q]) | ((unsigned)f2bf(b[2 * q + 1]) << 16);
                }
                *(uint4v*)&lA[m][kv] = v;
            }
        } else {
            const unsigned short* xb = (const unsigned short*)x_;
#pragma unroll
            for (int i = 0; i < 4; i++) {
                int m = (tid >> 3) + i * 32, kv = (tid & 7) * 8;
                *(uint4v*)&lA[m][kv] = *(const uint4v*)(xb + (size_t)lT[m] * D_DIM + k0 + kv);
            }
        }
#pragma unroll
        for (int i = 0; i < 2; i++) {
            int n = (tid >> 3) + i * 32, kc = (tid & 7) * 8;
            *(uint4v*)&lB1[n][kc] = *(const uint4v*)(W1 + (size_t)(n0 + n) * D_DIM + k0 + kc);
            *(uint4v*)&lB3[n][kc] = *(const uint4v*)(W3 + (size_t)(n0 + n) * D_DIM + k0 + kc);
        }
        __syncthreads();
#pragma unroll
        for (int kk = 0; kk < BK; kk += 32) {
            short8 af[4], b1f[2], b3f[2];
#pragma unroll
            for (int fm = 0; fm < 4; fm++) af[fm] = *(const short8*)&lA[wm + fm * 16 + lm][kk + lq * 8];
#pragma unroll
            for (int fn = 0; fn < 2; fn++) {
                b1f[fn] = *(const short8*)&lB1[wn + fn * 16 + lm][kk + lq * 8];
                b3f[fn] = *(const short8*)&lB3[wn + fn * 16 + lm][kk + lq * 8];
            }
#pragma unroll
            for (int fm = 0; fm < 4; fm++)
#pragma unroll
                for (int fn = 0; fn < 2; fn++) {
                    acc1[fm][fn] = __builtin_amdgcn_mfma_f32_16x16x32_bf16(af[fm], b1f[fn], acc1[fm][fn], 0, 0, 0);
                    acc3[fm][fn] = __builtin_amdgcn_mfma_f32_16x16x32_bf16(af[fm], b3f[fn], acc3[fm][fn], 0, 0, 0);
                }
        }
        __syncthreads();
    }
#pragma unroll
    for (int fm = 0; fm < 4; fm++)
#pragma unroll
        for (int r = 0; r < 4; r++) {
            int row = wm + fm * 16 + lq * 4 + r;
            float g = lG[row];
#pragma unroll
            for (int fn = 0; fn < 2; fn++) {
                float a1 = acc1[fm][fn][r], a3 = acc3[fm][fn][r];
                float h = a1 / (1.f + __expf(-a1)) * a3 * g;
                int col = wn + fn * 16 + lm;
                Abuf[(size_t)(slot0 + row) * H_DIM + n0 + col] = f2bf(h);
            }
        }
}

// ---------------------------------------------------------------------------
// Shared out: out[T,1024] = A_shared[T,1024] @ concat(sw2)[1024,1024], plain store
// grid (T/BM, D/BN)
// ---------------------------------------------------------------------------
__global__ __launch_bounds__(256, 2) void moe_out_shared_kernel(
    const unsigned short* __restrict__ Abuf, const unsigned short* __restrict__ w2t,
    const int* __restrict__ flag, void* __restrict__ out_)
{
    __shared__ __align__(16) unsigned short lA[BM][LDK];
    __shared__ __align__(16) unsigned short lB[BN][LDK];

    const int isf32 = *flag;
    const int tid = threadIdx.x;
    const int t0 = blockIdx.x * BM, n0 = blockIdx.y * BN;

    floatx4 acc[4][2];
#pragma unroll
    for (int fm = 0; fm < 4; fm++)
#pragma unroll
        for (int fn = 0; fn < 2; fn++) { floatx4 zz = {0.f,0.f,0.f,0.f}; acc[fm][fn] = zz; }
    const int wave = tid >> 6, lane = tid & 63;
    const int wm = (wave >> 1) * 64, wn = (wave & 1) * 32;
    const int lm = lane & 15, lq = lane >> 4;

    for (int k0 = 0; k0 < 2 * H_DIM; k0 += BK) {
        const unsigned short* W2 = w2t + (size_t)(8 + (k0 >> 9)) * D_DIM * H_DIM;  // [1024][512]
        const int kk0 = k0 & (H_DIM - 1);
#pragma unroll
        for (int i = 0; i < 4; i++) {
            int m = (tid >> 3) + i * 32, kv = (tid & 7) * 8;
            *(uint4v*)&lA[m][kv] = *(const uint4v*)(Abuf + (size_t)(t0 + m) * (2 * H_DIM) + k0 + kv);
        }
#pragma unroll
        for (int i = 0; i < 2; i++) {
            int n = (tid >> 3) + i * 32, kc = (tid & 7) * 8;
            *(uint4v*)&lB[n][kc] = *(const uint4v*)(W2 + (size_t)(n0 + n) * H_DIM + kk0 + kc);
        }
        __syncthreads();
#pragma unroll
        for (int kk = 0; kk < BK; kk += 32) {
            short8 af[4], bf[2];
#pragma unroll
            for (int fm = 0; fm < 4; fm++) af[fm] = *(const short8*)&lA[wm + fm * 16 + lm][kk + lq * 8];
#pragma unroll
            for (int fn = 0; fn < 2; fn++) bf[fn] = *(const short8*)&lB[wn + fn * 16 + lm][kk + lq * 8];
#pragma unroll
            for (int fm = 0; fm < 4; fm++)
#pragma unroll
                for (int fn = 0; fn < 2; fn++)
                    acc[fm][fn] = __builtin_amdgcn_mfma_f32_16x16x32_bf16(af[fm], bf[fn], acc[fm][fn], 0, 0, 0);
        }
        __syncthreads();
    }
#pragma unroll
    for (int fm = 0; fm < 4; fm++)
#pragma unroll
        for (int r = 0; r < 4; r++) {
            int row = wm + fm * 16 + lq * 4 + r;
#pragma unroll
            for (int fn = 0; fn < 2; fn++) {
                int col = wn + fn * 16 + lm;
                size_t off = (size_t)(t0 + row) * D_DIM + n0 + col;
                float val = acc[fm][fn][r];
                if (isf32) ((float*)out_)[off] = val;
                else       ((unsigned short*)out_)[off] = f2bf(val);
            }
        }
}

// ---------------------------------------------------------------------------
// Routed out: O_r[slot,1024] = A_routed[slot,512] @ w2_e[512,1024] (bf16 store)
// grid (maxseg, D/BN)
// ---------------------------------------------------------------------------
__global__ __launch_bounds__(256, 2) void moe_out_routed_kernel(
    const unsigned short* __restrict__ Abuf, const unsigned short* __restrict__ w2t,
    const int2* __restrict__ segdesc, const int* __restrict__ nseg,
    unsigned short* __restrict__ Or)
{
    __shared__ __align__(16) unsigned short lA[BM][LDK];
    __shared__ __align__(16) unsigned short lB[BN][LDK];

    const int s = blockIdx.x;
    if (s >= *nseg) return;
    const int tid = threadIdx.x;
    const int2 sd = segdesc[s];
    const int e = sd.x, slot0 = sd.y;
    const int n0 = blockIdx.y * BN;
    const unsigned short* W2 = w2t + (size_t)e * D_DIM * H_DIM;  // [1024][512]

    floatx4 acc[4][2];
#pragma unroll
    for (int fm = 0; fm < 4; fm++)
#pragma unroll
        for (int fn = 0; fn < 2; fn++) { floatx4 zz = {0.f,0.f,0.f,0.f}; acc[fm][fn] = zz; }
    const int wave = tid >> 6, lane = tid & 63;
    const int wm = (wave >> 1) * 64, wn = (wave & 1) * 32;
    const int lm = lane & 15, lq = lane >> 4;

    for (int k0 = 0; k0 < H_DIM; k0 += BK) {
#pragma unroll
        for (int i = 0; i < 4; i++) {
            int m = (tid >> 3) + i * 32, kv = (tid & 7) * 8;
            *(uint4v*)&lA[m][kv] = *(const uint4v*)(Abuf + (size_t)(slot0 + m) * H_DIM + k0 + kv);
        }
#pragma unroll
        for (int i = 0; i < 2; i++) {
            int n = (tid >> 3) + i * 32, kc = (tid & 7) * 8;
            *(uint4v*)&lB[n][kc] = *(const uint4v*)(W2 + (size_t)(n0 + n) * H_DIM + k0 + kc);
        }
        __syncthreads();
#pragma unroll
        for (int kk = 0; kk < BK; kk += 32) {
            short8 af[4], bf[2];
#pragma unroll
            for (int fm = 0; fm < 4; fm++) af[fm] = *(const short8*)&lA[wm + fm * 16 + lm][kk + lq * 8];
#pragma unroll
            for (int fn = 0; fn < 2; fn++) bf[fn] = *(const short8*)&lB[wn + fn * 16 + lm][kk + lq * 8];
#pragma unroll
            for (int fm = 0; fm < 4; fm++)
#pragma unroll
                for (int fn = 0; fn < 2; fn++)
                    acc[fm][fn] = __builtin_amdgcn_mfma_f32_16x16x32_bf16(af[fm], bf[fn], acc[fm][fn], 0, 0, 0);
        }
        __syncthreads();
    }
#pragma unroll
    for (int fm = 0; fm < 4; fm++)
#pragma unroll
        for (int r = 0; r < 4; r++) {
            int row = wm + fm * 16 + lq * 4 + r;
#pragma unroll
            for (int fn = 0; fn < 2; fn++) {
                int col = wn + fn * 16 + lm;
                Or[(size_t)(slot0 + row) * D_DIM + n0 + col] = f2bf(acc[fm][fn][r]);
            }
        }
}

// ---------------------------------------------------------------------------
// combine: out[t] += O_r[slot0(t)] + O_r[slot1(t)]   (grid T blocks, 256 thr x4)
// ---------------------------------------------------------------------------
__global__ __launch_bounds__(256) void combine_kernel(
    const unsigned short* __restrict__ Or, const int2* __restrict__ slotof,
    const int* __restrict__ flag, void* __restrict__ out_)
{
    const int isf32 = *flag;
    const int t = blockIdx.x;
    const int c = threadIdx.x * 4;
    const int2 so = slotof[t];
    uint2v u0 = *(const uint2v*)(Or + (size_t)so.x * D_DIM + c);
    uint2v u1 = *(const uint2v*)(Or + (size_t)so.y * D_DIM + c);
    float r[4];
#pragma unroll
    for (int q = 0; q < 2; q++) {
        r[2 * q]     = bf2f((unsigned short)(u0[q] & 0xFFFFu)) + bf2f((unsigned short)(u1[q] & 0xFFFFu));
        r[2 * q + 1] = bf2f((unsigned short)(u0[q] >> 16))     + bf2f((unsigned short)(u1[q] >> 16));
    }
    if (isf32) {
        float* op = (float*)out_ + (size_t)t * D_DIM + c;
        float4v o = *(float4v*)op;
#pragma unroll
        for (int q = 0; q < 4; q++) o[q] += r[q];
        *(float4v*)op = o;
    } else {
        unsigned short* op = (unsigned short*)out_ + (size_t)t * D_DIM + c;
        uint2v o = *(uint2v*)op;
        uint2v w;
#pragma unroll
        for (int q = 0; q < 2; q++) {
            float lo = bf2f((unsigned short)(o[q] & 0xFFFFu)) + r[2 * q];
            float hi = bf2f((unsigned short)(o[q] >> 16)) + r[2 * q + 1];
            w[q] = (unsigned)f2bf(lo) | ((unsigned)f2bf(hi) << 16);
        }
        *(uint2v*)op = w;
    }
}

// ---------------------------------------------------------------------------
extern "C" void kernel_launch(void* const* d_in, const int* in_sizes, int n_in,
                              void* d_out, int out_size, void* d_ws, size_t ws_size,
                              hipStream_t stream)
{
    const void* x   = d_in[0];
    const void* rw  = d_in[1];
    const void* rb  = d_in[2];
    const void* rw1 = d_in[3];
    const void* rw3 = d_in[4];
    const void* rw2 = d_in[5];
    const void* sw1 = d_in[6];
    const void* sw3 = d_in[7];
    const void* sw2 = d_in[8];

    const int T = in_sizes[0] / D_DIM;          // 4096
    const int SLOT_MAX = 2 * T + NEXP * BM;     // padded slot capacity
    const int maxseg = SLOT_MAX / BM;

    char* p = (char*)d_ws;
    int*    flag     = (int*)p;
    int*    cnt      = (int*)(p + 64);
    int*    fill     = (int*)(p + 128);
    int*    nseg     = (int*)(p + 192);
    int2*   segdesc  = (int2*)(p + 256);
    size_t  o = 2048;
    int*    topkE    = (int*)(p + o);    o += (size_t)4 * T;
    float2* topkG    = (float2*)(p + o); o += (size_t)8 * T;
    int2*   slotof   = (int2*)(p + o);   o += (size_t)8 * T;
    int*    toklist  = (int*)(p + o);    o += (size_t)4 * SLOT_MAX;
    float*  slotgate = (float*)(p + o);  o += (size_t)4 * SLOT_MAX;
    o = (o + 255) & ~(size_t)255;
    unsigned short* w2t = (unsigned short*)(p + o); o += (size_t)NP * D_DIM * H_DIM * 2;
    unsigned short* w1t = (unsigned short*)(p + o); o += (size_t)NP * H_DIM * D_DIM * 2;
    unsigned short* w3t = (unsigned short*)(p + o); o += (size_t)NP * H_DIM * D_DIM * 2;
    unsigned short* Or  = w1t;   // overlay: w1t+w3t (20MB) dead before moe_out_routed
    size_t abElems = (size_t)T * (2 * H_DIM);
    if ((size_t)SLOT_MAX * H_DIM > abElems) abElems = (size_t)SLOT_MAX * H_DIM;
    unsigned short* Abuf = (unsigned short*)(p + o); o += abElems * 2;
    (void)ws_size;

    detect_kernel<<<1, 256, 0, stream>>>((const unsigned short*)x, flag);
    init_kernel<<<(SLOT_MAX + 255) / 256, 256, 0, stream>>>(cnt, toklist, slotgate, SLOT_MAX);
    transp_kernel<<<dim3(D_DIM / 32, H_DIM / 64, NP), 256, 0, stream>>>(rw1, sw1, w1t, D_DIM, H_DIM, flag);
    transp_kernel<<<dim3(D_DIM / 32, H_DIM / 64, NP), 256, 0, stream>>>(rw3, sw3, w3t, D_DIM, H_DIM, flag);
    transp_kernel<<<dim3(H_DIM / 32, D_DIM / 64, NP), 256, 0, stream>>>(rw2, sw2, w2t, H_DIM, D_DIM, flag);
    router_kernel<<<T / 4, 256, 0, stream>>>(x, rw, rb, flag, topkE, topkG, cnt, T);
    seg_kernel<<<1, 64, 0, stream>>>(cnt, fill, segdesc, nseg);
    gather_kernel<<<(T + 255) / 256, 256, 0, stream>>>(topkE, topkG, fill, toklist, slotgate, slotof, T);
    moe_h_shared_kernel<<<dim3(T / BM, H_DIM / BN, 2), 256, 0, stream>>>(x, w1t, w3t, flag, Abuf);
    moe_out_shared_kernel<<<dim3(T / BM, D_DIM / BN), 256, 0, stream>>>(Abuf, w2t, flag, d_out);
    moe_h_routed_kernel<<<dim3(maxseg, H_DIM / BN), 256, 0, stream>>>(
        x, w1t, w3t, flag, toklist, slotgate, segdesc, nseg, Abuf);
    moe_out_routed_kernel<<<dim3(maxseg, D_DIM / BN), 256, 0, stream>>>(Abuf, w2t, segdesc, nseg, Or);
    combine_kernel<<<T, 256, 0, stream>>>(Or, slotof, flag, d_out);
}

// Round 4
// 357.034 us; speedup vs baseline: 1.2850x; 1.2732x over previous
//
#include <hip/hip_runtime.h>
#include <stdint.h>

#define D_DIM 1024
#define H_DIM 512
#define NEXP  8
#define NP    10            // 8 routed + 2 shared expert passes

#define BM 128
#define BN 64
#define BK 64
#define LDK 72              // BK + 8 pad -> 144B row stride (16B aligned)

typedef __attribute__((ext_vector_type(8))) short short8;     // 8 bf16 MFMA operand
typedef __attribute__((ext_vector_type(4))) float floatx4;    // MFMA accumulator
typedef __attribute__((ext_vector_type(4))) unsigned int uint4v;
typedef __attribute__((ext_vector_type(4))) float float4v;
typedef __attribute__((ext_vector_type(2))) unsigned int uint2v;

__device__ __forceinline__ float bf2f(unsigned short u) {
    union { float f; unsigned int i; } v; v.i = ((unsigned int)u) << 16; return v.f;
}
__device__ __forceinline__ unsigned short f2bf(float f) {
    union { float f; unsigned int i; } v; v.f = f;
    unsigned int r = v.i + 0x7FFFu + ((v.i >> 16) & 1u);   // RNE
    return (unsigned short)(r >> 16);
}

// ---------------------------------------------------------------------------
// Dtype detection (fp32-read-as-bf16 has uniform exponents -> e>=0xA0 certain)
// ---------------------------------------------------------------------------
__global__ void detect_kernel(const unsigned short* __restrict__ x, int* flag)
{
    __shared__ int bad;
    if (threadIdx.x == 0) bad = 0;
    __syncthreads();
    int b = 0;
    for (int i = threadIdx.x; i < 8192; i += 256) {
        int e = (x[i] >> 7) & 0xFF;
        if (e >= 0xA0) b = 1;
    }
    if (b) atomicOr(&bad, 1);
    __syncthreads();
    if (threadIdx.x == 0) *flag = bad;
}

// ---------------------------------------------------------------------------
// Weight transpose+convert: src [nmat][K][N] (fp32 or bf16) -> dst bf16 [nmat][N][K]
// ---------------------------------------------------------------------------
__global__ __launch_bounds__(256) void transp_kernel(
    const void* __restrict__ rsrc, const void* __restrict__ ssrc,
    unsigned short* __restrict__ dst, int K, int N, const int* __restrict__ flag)
{
    const int isf32 = *flag;
    const int z = blockIdx.z;
    const size_t moff = (size_t)(z < 8 ? z : z - 8) * K * N;
    const int nl = threadIdx.x & 63, j = threadIdx.x >> 6;
    const int n = blockIdx.y * 64 + nl;
    const int k0 = blockIdx.x * 32 + j * 8;

    unsigned short v[8];
    if (isf32) {
        const float* src = (const float*)(z < 8 ? rsrc : ssrc) + moff;
#pragma unroll
        for (int j2 = 0; j2 < 8; j2++) v[j2] = f2bf(src[(size_t)(k0 + j2) * N + n]);
    } else {
        const unsigned short* src = (const unsigned short*)(z < 8 ? rsrc : ssrc) + moff;
#pragma unroll
        for (int j2 = 0; j2 < 8; j2++) v[j2] = src[(size_t)(k0 + j2) * N + n];
    }
    uint4v w;
#pragma unroll
    for (int q = 0; q < 4; q++) w[q] = (unsigned)v[2 * q] | ((unsigned)v[2 * q + 1] << 16);
    *(uint4v*)(dst + ((size_t)z * N + n) * K + k0) = w;
}

// ---------------------------------------------------------------------------
// Router: one wave per token -> top-2 expert ids + softmax gates. NO atomics.
// ---------------------------------------------------------------------------
__global__ __launch_bounds__(256, 4) void router_kernel(
    const void* __restrict__ xv_, const void* __restrict__ rwv_,
    const void* __restrict__ rbv_, const int* __restrict__ flag,
    int* __restrict__ topkE, float2* __restrict__ topkG, int T)
{
    const int isf32 = *flag;
    int gid  = blockIdx.x * blockDim.x + threadIdx.x;
    int t    = gid >> 6;
    int lane = threadIdx.x & 63;
    if (t >= T) return;

    float acc[NEXP];
#pragma unroll
    for (int e = 0; e < NEXP; e++) acc[e] = 0.f;

    if (isf32) {
        const float* xr = (const float*)xv_ + (size_t)t * D_DIM;
        const float* rw = (const float*)rwv_;
#pragma unroll 4
        for (int i = 0; i < D_DIM / 64; i++) {
            int d = i * 64 + lane;
            float xv = xr[d];
            float4v wa = *(const float4v*)(rw + (size_t)d * NEXP);
            float4v wb = *(const float4v*)(rw + (size_t)d * NEXP + 4);
#pragma unroll
            for (int q = 0; q < 4; q++) { acc[q] += xv * wa[q]; acc[q + 4] += xv * wb[q]; }
        }
    } else {
        const unsigned short* xr = (const unsigned short*)xv_ + (size_t)t * D_DIM;
        const unsigned short* rw = (const unsigned short*)rwv_;
#pragma unroll 4
        for (int i = 0; i < D_DIM / 64; i++) {
            int d = i * 64 + lane;
            float xv = bf2f(xr[d]);
            uint4v wv = *(const uint4v*)(rw + (size_t)d * NEXP);
#pragma unroll
            for (int q = 0; q < 4; q++) {
                unsigned int w = wv[q];
                acc[q * 2 + 0] += xv * bf2f((unsigned short)(w & 0xFFFFu));
                acc[q * 2 + 1] += xv * bf2f((unsigned short)(w >> 16));
            }
        }
    }
#pragma unroll
    for (int m = 32; m >= 1; m >>= 1) {
#pragma unroll
        for (int e = 0; e < NEXP; e++) acc[e] += __shfl_xor(acc[e], m, 64);
    }
    if (lane == 0) {
#pragma unroll
        for (int e = 0; e < NEXP; e++)
            acc[e] += isf32 ? ((const float*)rbv_)[e] : bf2f(((const unsigned short*)rbv_)[e]);
        int i1 = 0; float v1 = acc[0];
#pragma unroll
        for (int e = 1; e < NEXP; e++) if (acc[e] > v1) { v1 = acc[e]; i1 = e; }
        int i2 = -1; float v2 = -3.4e38f;
#pragma unroll
        for (int e = 0; e < NEXP; e++) if (e != i1 && acc[e] > v2) { v2 = acc[e]; i2 = e; }
        float g1 = 1.f / (1.f + __expf(v2 - v1));   // v2 <= v1: stable softmax2
        float g2 = 1.f - g1;
        topkE[t] = i1 | (i2 << 8);
        float2 g; g.x = g1; g.y = g2;
        topkG[t] = g;
    }
}

// ---------------------------------------------------------------------------
// segcnt: single wave. Count tokens/expert (register histogram + shuffle
// reduce, NO atomics), build padded segment table, zero pad slots, set fill
// bases (64B-padded: fill[e*16]).
// ---------------------------------------------------------------------------
__global__ void segcnt_kernel(const int* __restrict__ topkE, int T,
                              int* __restrict__ fill, int2* __restrict__ segdesc,
                              int* __restrict__ nseg, int* __restrict__ toklist,
                              float* __restrict__ slotgate)
{
    const int lane = threadIdx.x;   // 64 threads
    int c[NEXP];
#pragma unroll
    for (int e = 0; e < NEXP; e++) c[e] = 0;
    for (int i = lane; i < T; i += 64) {
        int pk = topkE[i];
        int e0 = pk & 255, e1 = pk >> 8;
#pragma unroll
        for (int e = 0; e < NEXP; e++) c[e] += (e0 == e) + (e1 == e);
    }
#pragma unroll
    for (int m = 32; m >= 1; m >>= 1) {
#pragma unroll
        for (int e = 0; e < NEXP; e++) c[e] += __shfl_xor(c[e], m, 64);
    }
    // all lanes hold identical totals now
    int base[NEXP + 1];
    base[0] = 0;
#pragma unroll
    for (int e = 0; e < NEXP; e++) {
        int nsg = (c[e] + BM - 1) / BM;
        base[e + 1] = base[e] + nsg * BM;
    }
    if (lane == 0) {
        int ns = 0;
        for (int e = 0; e < NEXP; e++)
            for (int b = base[e]; b < base[e + 1]; b += BM) {
                int2 s; s.x = e; s.y = b; segdesc[ns++] = s;
            }
        *nseg = ns;
    }
    if (lane < NEXP) fill[lane * 16] = base[lane];
    // zero pad slots (token 0, gate 0): [base[e]+c[e], base[e+1])
    for (int e = 0; e < NEXP; e++)
        for (int i = base[e] + c[e] + lane; i < base[e + 1]; i += 64) {
            toklist[i] = 0; slotgate[i] = 0.f;
        }
}

// ---------------------------------------------------------------------------
// gather: hierarchical slot assignment. LDS histogram per block, ONE global
// atomicAdd per (block,expert) on 64B-padded fill, LDS-rank within block.
// ---------------------------------------------------------------------------
__global__ __launch_bounds__(256) void gather_kernel(
    const int* __restrict__ topkE, const float2* __restrict__ topkG,
    int* __restrict__ fill, int* __restrict__ toklist,
    float* __restrict__ slotgate, int2* __restrict__ slotof, int T)
{
    __shared__ int hist[NEXP], sbase[NEXP], rank[NEXP];
    const int tid = threadIdx.x;
    if (tid < NEXP) { hist[tid] = 0; rank[tid] = 0; }
    __syncthreads();
    const int t = blockIdx.x * 256 + tid;
    int e0 = 0, e1 = 0; float2 g; g.x = 0.f; g.y = 0.f;
    const bool valid = (t < T);
    if (valid) {
        int pk = topkE[t]; g = topkG[t];
        e0 = pk & 255; e1 = pk >> 8;
        atomicAdd(&hist[e0], 1);
        atomicAdd(&hist[e1], 1);
    }
    __syncthreads();
    if (tid < NEXP) sbase[tid] = atomicAdd(&fill[tid * 16], hist[tid]);
    __syncthreads();
    if (valid) {
        int s0 = sbase[e0] + atomicAdd(&rank[e0], 1);
        int s1 = sbase[e1] + atomicAdd(&rank[e1], 1);
        toklist[s0] = t; slotgate[s0] = g.x;
        toklist[s1] = t; slotgate[s1] = g.y;
        int2 so; so.x = s0; so.y = s1;
        slotof[t] = so;
    }
}

// ---------------------------------------------------------------------------
// Shared-expert hidden: A_shared[t, z*512+h] = silu(x@w1_sh)*(x@w3_sh)  (bf16)
// ---------------------------------------------------------------------------
__global__ __launch_bounds__(256, 2) void moe_h_shared_kernel(
    const void* __restrict__ x_, const unsigned short* __restrict__ w1t,
    const unsigned short* __restrict__ w3t, const int* __restrict__ flag,
    unsigned short* __restrict__ Abuf)
{
    __shared__ __align__(16) unsigned short lA[BM][LDK];
    __shared__ __align__(16) unsigned short lB1[BN][LDK];
    __shared__ __align__(16) unsigned short lB3[BN][LDK];

    const int isf32 = *flag;
    const int tid = threadIdx.x;
    const int t0 = blockIdx.x * BM, n0 = blockIdx.y * BN, z = blockIdx.z;
    const unsigned short* W1 = w1t + (size_t)(8 + z) * H_DIM * D_DIM;  // [512][1024]
    const unsigned short* W3 = w3t + (size_t)(8 + z) * H_DIM * D_DIM;

    floatx4 acc1[4][2], acc3[4][2];
#pragma unroll
    for (int fm = 0; fm < 4; fm++)
#pragma unroll
        for (int fn = 0; fn < 2; fn++) {
            floatx4 zz = {0.f, 0.f, 0.f, 0.f};
            acc1[fm][fn] = zz; acc3[fm][fn] = zz;
        }
    const int wave = tid >> 6, lane = tid & 63;
    const int wm = (wave >> 1) * 64, wn = (wave & 1) * 32;
    const int lm = lane & 15, lq = lane >> 4;

    for (int k0 = 0; k0 < D_DIM; k0 += BK) {
        if (isf32) {
            const float* xf = (const float*)x_;
#pragma unroll
            for (int i = 0; i < 4; i++) {
                int m = (tid >> 3) + i * 32, kv = (tid & 7) * 8;
                const float* src = xf + (size_t)(t0 + m) * D_DIM + k0 + kv;
                float4v a = *(const float4v*)src, b = *(const float4v*)(src + 4);
                uint4v v;
#pragma unroll
                for (int q = 0; q < 2; q++) {
                    v[q]     = (unsigned)f2bf(a[2 * q]) | ((unsigned)f2bf(a[2 * q + 1]) << 16);
                    v[q + 2] = (unsigned)f2bf(b[2 * q]) | ((unsigned)f2bf(b[2 * q + 1]) << 16);
                }
                *(uint4v*)&lA[m][kv] = v;
            }
        } else {
            const unsigned short* xb = (const unsigned short*)x_;
#pragma unroll
            for (int i = 0; i < 4; i++) {
                int m = (tid >> 3) + i * 32, kv = (tid & 7) * 8;
                *(uint4v*)&lA[m][kv] = *(const uint4v*)(xb + (size_t)(t0 + m) * D_DIM + k0 + kv);
            }
        }
#pragma unroll
        for (int i = 0; i < 2; i++) {
            int n = (tid >> 3) + i * 32, kc = (tid & 7) * 8;
            *(uint4v*)&lB1[n][kc] = *(const uint4v*)(W1 + (size_t)(n0 + n) * D_DIM + k0 + kc);
            *(uint4v*)&lB3[n][kc] = *(const uint4v*)(W3 + (size_t)(n0 + n) * D_DIM + k0 + kc);
        }
        __syncthreads();
#pragma unroll
        for (int kk = 0; kk < BK; kk += 32) {
            short8 af[4], b1f[2], b3f[2];
#pragma unroll
            for (int fm = 0; fm < 4; fm++) af[fm] = *(const short8*)&lA[wm + fm * 16 + lm][kk + lq * 8];
#pragma unroll
            for (int fn = 0; fn < 2; fn++) {
                b1f[fn] = *(const short8*)&lB1[wn + fn * 16 + lm][kk + lq * 8];
                b3f[fn] = *(const short8*)&lB3[wn + fn * 16 + lm][kk + lq * 8];
            }
#pragma unroll
            for (int fm = 0; fm < 4; fm++)
#pragma unroll
                for (int fn = 0; fn < 2; fn++) {
                    acc1[fm][fn] = __builtin_amdgcn_mfma_f32_16x16x32_bf16(af[fm], b1f[fn], acc1[fm][fn], 0, 0, 0);
                    acc3[fm][fn] = __builtin_amdgcn_mfma_f32_16x16x32_bf16(af[fm], b3f[fn], acc3[fm][fn], 0, 0, 0);
                }
        }
        __syncthreads();
    }
#pragma unroll
    for (int fm = 0; fm < 4; fm++)
#pragma unroll
        for (int r = 0; r < 4; r++) {
            int row = wm + fm * 16 + lq * 4 + r;
#pragma unroll
            for (int fn = 0; fn < 2; fn++) {
                float a1 = acc1[fm][fn][r], a3 = acc3[fm][fn][r];
                float h = a1 / (1.f + __expf(-a1)) * a3;
                int col = wn + fn * 16 + lm;
                Abuf[(size_t)(t0 + row) * (2 * H_DIM) + z * H_DIM + n0 + col] = f2bf(h);
            }
        }
}

// ---------------------------------------------------------------------------
// Routed hidden: gathered token rows, gate folded in. grid (maxseg, H/BN)
// ---------------------------------------------------------------------------
__global__ __launch_bounds__(256, 2) void moe_h_routed_kernel(
    const void* __restrict__ x_, const unsigned short* __restrict__ w1t,
    const unsigned short* __restrict__ w3t, const int* __restrict__ flag,
    const int* __restrict__ toklist, const float* __restrict__ slotgate,
    const int2* __restrict__ segdesc, const int* __restrict__ nseg,
    unsigned short* __restrict__ Abuf)
{
    __shared__ __align__(16) unsigned short lA[BM][LDK];
    __shared__ __align__(16) unsigned short lB1[BN][LDK];
    __shared__ __align__(16) unsigned short lB3[BN][LDK];
    __shared__ int   lT[BM];
    __shared__ float lG[BM];

    const int s = blockIdx.x;
    if (s >= *nseg) return;
    const int isf32 = *flag;
    const int tid = threadIdx.x;
    const int2 sd = segdesc[s];
    const int e = sd.x, slot0 = sd.y;
    const int n0 = blockIdx.y * BN;
    const unsigned short* W1 = w1t + (size_t)e * H_DIM * D_DIM;
    const unsigned short* W3 = w3t + (size_t)e * H_DIM * D_DIM;

    if (tid < BM) { lT[tid] = toklist[slot0 + tid]; lG[tid] = slotgate[slot0 + tid]; }
    __syncthreads();

    floatx4 acc1[4][2], acc3[4][2];
#pragma unroll
    for (int fm = 0; fm < 4; fm++)
#pragma unroll
        for (int fn = 0; fn < 2; fn++) {
            floatx4 zz = {0.f, 0.f, 0.f, 0.f};
            acc1[fm][fn] = zz; acc3[fm][fn] = zz;
        }
    const int wave = tid >> 6, lane = tid & 63;
    const int wm = (wave >> 1) * 64, wn = (wave & 1) * 32;
    const int lm = lane & 15, lq = lane >> 4;

    for (int k0 = 0; k0 < D_DIM; k0 += BK) {
        if (isf32) {
            const float* xf = (const float*)x_;
#pragma unroll
            for (int i = 0; i < 4; i++) {
                int m = (tid >> 3) + i * 32, kv = (tid & 7) * 8;
                const float* src = xf + (size_t)lT[m] * D_DIM + k0 + kv;
                float4v a = *(const float4v*)src, b = *(const float4v*)(src + 4);
                uint4v v;
#pragma unroll
                for (int q = 0; q < 2; q++) {
                    v[q]     = (unsigned)f2bf(a[2 * q]) | ((unsigned)f2bf(a[2 * q + 1]) << 16);
                    v[q + 2] = (unsigned)f2bf(b[2 * q]) | ((unsigned)f2bf(b[2 * q + 1]) << 16);
                }
                *(uint4v*)&lA[m][kv] = v;
            }
        } else {
            const unsigned short* xb = (const unsigned short*)x_;
#pragma unroll
            for (int i = 0; i < 4; i++) {
                int m = (tid >> 3) + i * 32, kv = (tid & 7) * 8;
                *(uint4v*)&lA[m][kv] = *(const uint4v*)(xb + (size_t)lT[m] * D_DIM + k0 + kv);
            }
        }
#pragma unroll
        for (int i = 0; i < 2; i++) {
            int n = (tid >> 3) + i * 32, kc = (tid & 7) * 8;
            *(uint4v*)&lB1[n][kc] = *(const uint4v*)(W1 + (size_t)(n0 + n) * D_DIM + k0 + kc);
            *(uint4v*)&lB3[n][kc] = *(const uint4v*)(W3 + (size_t)(n0 + n) * D_DIM + k0 + kc);
        }
        __syncthreads();
#pragma unroll
        for (int kk = 0; kk < BK; kk += 32) {
            short8 af[4], b1f[2], b3f[2];
#pragma unroll
            for (int fm = 0; fm < 4; fm++) af[fm] = *(const short8*)&lA[wm + fm * 16 + lm][kk + lq * 8];
#pragma unroll
            for (int fn = 0; fn < 2; fn++) {
                b1f[fn] = *(const short8*)&lB1[wn + fn * 16 + lm][kk + lq * 8];
                b3f[fn] = *(const short8*)&lB3[wn + fn * 16 + lm][kk + lq * 8];
            }
#pragma unroll
            for (int fm = 0; fm < 4; fm++)
#pragma unroll
                for (int fn = 0; fn < 2; fn++) {
                    acc1[fm][fn] = __builtin_amdgcn_mfma_f32_16x16x32_bf16(af[fm], b1f[fn], acc1[fm][fn], 0, 0, 0);
                    acc3[fm][fn] = __builtin_amdgcn_mfma_f32_16x16x32_bf16(af[fm], b3f[fn], acc3[fm][fn], 0, 0, 0);
                }
        }
        __syncthreads();
    }
#pragma unroll
    for (int fm = 0; fm < 4; fm++)
#pragma unroll
        for (int r = 0; r < 4; r++) {
            int row = wm + fm * 16 + lq * 4 + r;
            float g = lG[row];
#pragma unroll
            for (int fn = 0; fn < 2; fn++) {
                float a1 = acc1[fm][fn][r], a3 = acc3[fm][fn][r];
                float h = a1 / (1.f + __expf(-a1)) * a3 * g;
                int col = wn + fn * 16 + lm;
                Abuf[(size_t)(slot0 + row) * H_DIM + n0 + col] = f2bf(h);
            }
        }
}

// ---------------------------------------------------------------------------
// Shared out: out[T,1024] = A_shared[T,1024] @ concat(sw2)[1024,1024]
// ---------------------------------------------------------------------------
__global__ __launch_bounds__(256, 2) void moe_out_shared_kernel(
    const unsigned short* __restrict__ Abuf, const unsigned short* __restrict__ w2t,
    const int* __restrict__ flag, void* __restrict__ out_)
{
    __shared__ __align__(16) unsigned short lA[BM][LDK];
    __shared__ __align__(16) unsigned short lB[BN][LDK];

    const int isf32 = *flag;
    const int tid = threadIdx.x;
    const int t0 = blockIdx.x * BM, n0 = blockIdx.y * BN;

    floatx4 acc[4][2];
#pragma unroll
    for (int fm = 0; fm < 4; fm++)
#pragma unroll
        for (int fn = 0; fn < 2; fn++) { floatx4 zz = {0.f,0.f,0.f,0.f}; acc[fm][fn] = zz; }
    const int wave = tid >> 6, lane = tid & 63;
    const int wm = (wave >> 1) * 64, wn = (wave & 1) * 32;
    const int lm = lane & 15, lq = lane >> 4;

    for (int k0 = 0; k0 < 2 * H_DIM; k0 += BK) {
        const unsigned short* W2 = w2t + (size_t)(8 + (k0 >> 9)) * D_DIM * H_DIM;  // [1024][512]
        const int kk0 = k0 & (H_DIM - 1);
#pragma unroll
        for (int i = 0; i < 4; i++) {
            int m = (tid >> 3) + i * 32, kv = (tid & 7) * 8;
            *(uint4v*)&lA[m][kv] = *(const uint4v*)(Abuf + (size_t)(t0 + m) * (2 * H_DIM) + k0 + kv);
        }
#pragma unroll
        for (int i = 0; i < 2; i++) {
            int n = (tid >> 3) + i * 32, kc = (tid & 7) * 8;
            *(uint4v*)&lB[n][kc] = *(const uint4v*)(W2 + (size_t)(n0 + n) * H_DIM + kk0 + kc);
        }
        __syncthreads();
#pragma unroll
        for (int kk = 0; kk < BK; kk += 32) {
            short8 af[4], bf[2];
#pragma unroll
            for (int fm = 0; fm < 4; fm++) af[fm] = *(const short8*)&lA[wm + fm * 16 + lm][kk + lq * 8];
#pragma unroll
            for (int fn = 0; fn < 2; fn++) bf[fn] = *(const short8*)&lB[wn + fn * 16 + lm][kk + lq * 8];
#pragma unroll
            for (int fm = 0; fm < 4; fm++)
#pragma unroll
                for (int fn = 0; fn < 2; fn++)
                    acc[fm][fn] = __builtin_amdgcn_mfma_f32_16x16x32_bf16(af[fm], bf[fn], acc[fm][fn], 0, 0, 0);
        }
        __syncthreads();
    }
#pragma unroll
    for (int fm = 0; fm < 4; fm++)
#pragma unroll
        for (int r = 0; r < 4; r++) {
            int row = wm + fm * 16 + lq * 4 + r;
#pragma unroll
            for (int fn = 0; fn < 2; fn++) {
                int col = wn + fn * 16 + lm;
                size_t off = (size_t)(t0 + row) * D_DIM + n0 + col;
                float val = acc[fm][fn][r];
                if (isf32) ((float*)out_)[off] = val;
                else       ((unsigned short*)out_)[off] = f2bf(val);
            }
        }
}

// ---------------------------------------------------------------------------
// Routed out: O_r[slot,1024] = A_routed[slot,512] @ w2_e[512,1024] (bf16 store)
// ---------------------------------------------------------------------------
__global__ __launch_bounds__(256, 2) void moe_out_routed_kernel(
    const unsigned short* __restrict__ Abuf, const unsigned short* __restrict__ w2t,
    const int2* __restrict__ segdesc, const int* __restrict__ nseg,
    unsigned short* __restrict__ Or)
{
    __shared__ __align__(16) unsigned short lA[BM][LDK];
    __shared__ __align__(16) unsigned short lB[BN][LDK];

    const int s = blockIdx.x;
    if (s >= *nseg) return;
    const int tid = threadIdx.x;
    const int2 sd = segdesc[s];
    const int e = sd.x, slot0 = sd.y;
    const int n0 = blockIdx.y * BN;
    const unsigned short* W2 = w2t + (size_t)e * D_DIM * H_DIM;  // [1024][512]

    floatx4 acc[4][2];
#pragma unroll
    for (int fm = 0; fm < 4; fm++)
#pragma unroll
        for (int fn = 0; fn < 2; fn++) { floatx4 zz = {0.f,0.f,0.f,0.f}; acc[fm][fn] = zz; }
    const int wave = tid >> 6, lane = tid & 63;
    const int wm = (wave >> 1) * 64, wn = (wave & 1) * 32;
    const int lm = lane & 15, lq = lane >> 4;

    for (int k0 = 0; k0 < H_DIM; k0 += BK) {
#pragma unroll
        for (int i = 0; i < 4; i++) {
            int m = (tid >> 3) + i * 32, kv = (tid & 7) * 8;
            *(uint4v*)&lA[m][kv] = *(const uint4v*)(Abuf + (size_t)(slot0 + m) * H_DIM + k0 + kv);
        }
#pragma unroll
        for (int i = 0; i < 2; i++) {
            int n = (tid >> 3) + i * 32, kc = (tid & 7) * 8;
            *(uint4v*)&lB[n][kc] = *(const uint4v*)(W2 + (size_t)(n0 + n) * H_DIM + k0 + kc);
        }
        __syncthreads();
#pragma unroll
        for (int kk = 0; kk < BK; kk += 32) {
            short8 af[4], bf[2];
#pragma unroll
            for (int fm = 0; fm < 4; fm++) af[fm] = *(const short8*)&lA[wm + fm * 16 + lm][kk + lq * 8];
#pragma unroll
            for (int fn = 0; fn < 2; fn++) bf[fn] = *(const short8*)&lB[wn + fn * 16 + lm][kk + lq * 8];
#pragma unroll
            for (int fm = 0; fm < 4; fm++)
#pragma unroll
                for (int fn = 0; fn < 2; fn++)
                    acc[fm][fn] = __builtin_amdgcn_mfma_f32_16x16x32_bf16(af[fm], bf[fn], acc[fm][fn], 0, 0, 0);
        }
        __syncthreads();
    }
#pragma unroll
    for (int fm = 0; fm < 4; fm++)
#pragma unroll
        for (int r = 0; r < 4; r++) {
            int row = wm + fm * 16 + lq * 4 + r;
#pragma unroll
            for (int fn = 0; fn < 2; fn++) {
                int col = wn + fn * 16 + lm;
                Or[(size_t)(slot0 + row) * D_DIM + n0 + col] = f2bf(acc[fm][fn][r]);
            }
        }
}

// ---------------------------------------------------------------------------
// combine: out[t] += O_r[slot0(t)] + O_r[slot1(t)]
// ---------------------------------------------------------------------------
__global__ __launch_bounds__(256) void combine_kernel(
    const unsigned short* __restrict__ Or, const int2* __restrict__ slotof,
    const int* __restrict__ flag, void* __restrict__ out_)
{
    const int isf32 = *flag;
    const int t = blockIdx.x;
    const int c = threadIdx.x * 4;
    const int2 so = slotof[t];
    uint2v u0 = *(const uint2v*)(Or + (size_t)so.x * D_DIM + c);
    uint2v u1 = *(const uint2v*)(Or + (size_t)so.y * D_DIM + c);
    float r[4];
#pragma unroll
    for (int q = 0; q < 2; q++) {
        r[2 * q]     = bf2f((unsigned short)(u0[q] & 0xFFFFu)) + bf2f((unsigned short)(u1[q] & 0xFFFFu));
        r[2 * q + 1] = bf2f((unsigned short)(u0[q] >> 16))     + bf2f((unsigned short)(u1[q] >> 16));
    }
    if (isf32) {
        float* op = (float*)out_ + (size_t)t * D_DIM + c;
        float4v o = *(float4v*)op;
#pragma unroll
        for (int q = 0; q < 4; q++) o[q] += r[q];
        *(float4v*)op = o;
    } else {
        unsigned short* op = (unsigned short*)out_ + (size_t)t * D_DIM + c;
        uint2v o = *(uint2v*)op;
        uint2v w;
#pragma unroll
        for (int q = 0; q < 2; q++) {
            float lo = bf2f((unsigned short)(o[q] & 0xFFFFu)) + r[2 * q];
            float hi = bf2f((unsigned short)(o[q] >> 16)) + r[2 * q + 1];
            w[q] = (unsigned)f2bf(lo) | ((unsigned)f2bf(hi) << 16);
        }
        *(uint2v*)op = w;
    }
}

// ---------------------------------------------------------------------------
extern "C" void kernel_launch(void* const* d_in, const int* in_sizes, int n_in,
                              void* d_out, int out_size, void* d_ws, size_t ws_size,
                              hipStream_t stream)
{
    const void* x   = d_in[0];
    const void* rw  = d_in[1];
    const void* rb  = d_in[2];
    const void* rw1 = d_in[3];
    const void* rw3 = d_in[4];
    const void* rw2 = d_in[5];
    const void* sw1 = d_in[6];
    const void* sw3 = d_in[7];
    const void* sw2 = d_in[8];

    const int T = in_sizes[0] / D_DIM;          // 4096
    const int SLOT_MAX = 2 * T + NEXP * BM;     // padded slot capacity
    const int maxseg = SLOT_MAX / BM;

    char* p = (char*)d_ws;
    int*    flag     = (int*)p;                 // 4B
    int*    nseg     = (int*)(p + 64);
    int*    fill     = (int*)(p + 128);         // 8 experts x 16 ints (64B padded)
    int2*   segdesc  = (int2*)(p + 768);        // up to 72 segs
    size_t  o = 2048;
    int*    topkE    = (int*)(p + o);    o += (size_t)4 * T;
    float2* topkG    = (float2*)(p + o); o += (size_t)8 * T;
    int2*   slotof   = (int2*)(p + o);   o += (size_t)8 * T;
    int*    toklist  = (int*)(p + o);    o += (size_t)4 * SLOT_MAX;
    float*  slotgate = (float*)(p + o);  o += (size_t)4 * SLOT_MAX;
    o = (o + 255) & ~(size_t)255;
    unsigned short* w2t = (unsigned short*)(p + o); o += (size_t)NP * D_DIM * H_DIM * 2;
    unsigned short* w1t = (unsigned short*)(p + o); o += (size_t)NP * H_DIM * D_DIM * 2;
    unsigned short* w3t = (unsigned short*)(p + o); o += (size_t)NP * H_DIM * D_DIM * 2;
    unsigned short* Or  = w1t;   // overlay: w1t+w3t (20MB) dead before moe_out_routed
    size_t abElems = (size_t)T * (2 * H_DIM);
    if ((size_t)SLOT_MAX * H_DIM > abElems) abElems = (size_t)SLOT_MAX * H_DIM;
    unsigned short* Abuf = (unsigned short*)(p + o); o += abElems * 2;
    (void)ws_size;

    detect_kernel<<<1, 256, 0, stream>>>((const unsigned short*)x, flag);
    transp_kernel<<<dim3(D_DIM / 32, H_DIM / 64, NP), 256, 0, stream>>>(rw1, sw1, w1t, D_DIM, H_DIM, flag);
    transp_kernel<<<dim3(D_DIM / 32, H_DIM / 64, NP), 256, 0, stream>>>(rw3, sw3, w3t, D_DIM, H_DIM, flag);
    transp_kernel<<<dim3(H_DIM / 32, D_DIM / 64, NP), 256, 0, stream>>>(rw2, sw2, w2t, H_DIM, D_DIM, flag);
    router_kernel<<<T / 4, 256, 0, stream>>>(x, rw, rb, flag, topkE, topkG, T);
    segcnt_kernel<<<1, 64, 0, stream>>>(topkE, T, fill, segdesc, nseg, toklist, slotgate);
    gather_kernel<<<(T + 255) / 256, 256, 0, stream>>>(topkE, topkG, fill, toklist, slotgate, slotof, T);
    moe_h_shared_kernel<<<dim3(T / BM, H_DIM / BN, 2), 256, 0, stream>>>(x, w1t, w3t, flag, Abuf);
    moe_out_shared_kernel<<<dim3(T / BM, D_DIM / BN), 256, 0, stream>>>(Abuf, w2t, flag, d_out);
    moe_h_routed_kernel<<<dim3(maxseg, H_DIM / BN), 256, 0, stream>>>(
        x, w1t, w3t, flag, toklist, slotgate, segdesc, nseg, Abuf);
    moe_out_routed_kernel<<<dim3(maxseg, D_DIM / BN), 256, 0, stream>>>(Abuf, w2t, segdesc, nseg, Or);
    combine_kernel<<<T, 256, 0, stream>>>(Or, slotof, flag, d_out);
}